// Round 13
// baseline (84.314 us; speedup 1.0000x reference)
//
#include <hip/hip_runtime.h>

#define B_ 4096
#define D_ 256
#define N_ 8192
// log2(e)/0.07
#define EXP2SC 20.60992915555662f

typedef float f32x4 __attribute__((ext_vector_type(4)));
typedef __bf16 bf16x8 __attribute__((ext_vector_type(8)));

__device__ __forceinline__ float fast_exp2(float x){
#if __has_builtin(__builtin_amdgcn_exp2f)
  return __builtin_amdgcn_exp2f(x);
#else
  return exp2f(x);
#endif
}

__device__ __forceinline__ unsigned short f2bf(float x){
  unsigned int u = __float_as_uint(x);
  unsigned int r = (u + 0x7fffu + ((u >> 16) & 1u)) >> 16;
  return (unsigned short)r;
}

// ------- kernel 1: pack labels + zero accumulators (r12-verified) -------
__global__ __launch_bounds__(256) void pack_kernel(const float* __restrict__ labels,
                                                   ulonglong2* __restrict__ bits,
                                                   int* __restrict__ scnt,
                                                   float* __restrict__ possum,
                                                   float* __restrict__ total,
                                                   int* __restrict__ poscnt){
  int i = blockIdx.x * 256 + threadIdx.x;      // 0..4095
  possum[i] = 0.f; total[i] = 0.f; poscnt[i] = 0;
  const float* L = labels + (size_t)i * 80;
  unsigned long long lo = 0ull, hi = 0ull;
  #pragma unroll
  for (int c = 0; c < 64; ++c) lo |= (L[c] > 0.5f) ? (1ull << c) : 0ull;
  #pragma unroll
  for (int c = 64; c < 80; ++c) hi |= (L[c] > 0.5f) ? (1ull << (c - 64)) : 0ull;
  bits[i] = make_ulonglong2(lo, hi);
  scnt[i] = __popcll(lo) + __popcll(hi);
}

// ------- kernel 2: f32 features -> bf16 contrast, FRAGMENT-MAJOR layout -------
// logical contrast[v*B + b][d] = f[b][v][d]; stored at (bytes)
// FM(row, c16) = (row>>4)<<13 | (c16>>2)<<10 | (c16&3)<<8 | (row&15)<<4
// so a wave's MFMA-fragment load is one contiguous 1KB burst. (r11-verified)
__global__ __launch_bounds__(256) void conv_kernel(const float* __restrict__ f,
                                                   unsigned short* __restrict__ ctr){
  int t = blockIdx.x * 256 + threadIdx.x;      // 0..262143, 8 elems each
  int row = t >> 5;                            // 0..8191
  int c   = t & 31;                            // 16B chunk 0..31
  int v = row >> 12, b = row & 4095;
  const float* src = f + ((((size_t)b << 1) + v) << 8) + (c << 3);
  float4 a = *(const float4*)src;
  float4 cc = *(const float4*)(src + 4);
  uint4 o;
  o.x = (unsigned)f2bf(a.x)  | ((unsigned)f2bf(a.y)  << 16);
  o.y = (unsigned)f2bf(a.z)  | ((unsigned)f2bf(a.w)  << 16);
  o.z = (unsigned)f2bf(cc.x) | ((unsigned)f2bf(cc.y) << 16);
  o.w = (unsigned)f2bf(cc.z) | ((unsigned)f2bf(cc.w) << 16);
  size_t oaddr = ((size_t)(row >> 4) << 13) + ((size_t)(c >> 2) << 10)
               + ((size_t)(c & 3) << 8) + ((size_t)(row & 15) << 4);
  *(uint4*)((char*)ctr + oaddr) = o;
}

// ------ kernel 3: Jaccard pos bitmask + fused per-row popcount ------
__global__ __launch_bounds__(256) void pos_kernel(const ulonglong2* __restrict__ bits,
                                                  const int* __restrict__ scnt,
                                                  unsigned long long* __restrict__ posw,
                                                  int* __restrict__ poscnt){
  __shared__ unsigned long long rbl[16], rbh[16];
  __shared__ int rs_sh[16];
  int tid = threadIdx.x;
  int bid = blockIdx.x;
  int i0 = (bid >> 4) << 4;                   // row group base
  int jm = ((bid & 15) << 8) + tid;           // this thread's column
  if (tid < 16){
    ulonglong2 bb = bits[i0 + tid];
    rbl[tid] = bb.x; rbh[tid] = bb.y;
    rs_sh[tid] = scnt[i0 + tid];
  }
  __syncthreads();
  ulonglong2 bj = bits[jm];
  int sj = scnt[jm];
  int lane = tid & 63;
  int wword = ((bid & 15) << 2) + (tid >> 6); // jm >> 6
  #pragma unroll
  for (int r = 0; r < 16; ++r){
    int inter = __popcll(rbl[r] & bj.x) + __popcll(rbh[r] & bj.y);
    int uni = rs_sh[r] + sj - inter;
    bool hit = false;
    if (2 * inter >= uni){                     // integer prefilter (superset)
      float sim = (float)inter / ((float)uni + 1e-6f);
      hit = (sim >= 0.5f);
    }
    unsigned long long m = __ballot(hit);
    if (lane == 0){
      posw[(size_t)(i0 + r) * 64 + wword] = m;
      if (m) atomicAdd(&poscnt[i0 + r], __popcll(m));  // sparse: ~2-3 hits/row
    }
  }
}

// ---- kernel 4: ZERO-LDS ZERO-BARRIER fused GEMM on fragment-major ctr ----
// 256 thr = 4 fully independent waves; each computes 32 rows x 128 cols, K=256.
// Fragment-major layout makes BOTH A and B fragment loads contiguous 1KB
// wave-bursts from global (r8's divergence disease structurally gone).
// No __shared__, no __syncthreads: residency bounded only by VGPR; all
// latency hidden by free-running waves (r11/r12 occupancy correlation).
__global__ __launch_bounds__(256) void gemm_kernel(const unsigned short* __restrict__ ctr,
                                                   const unsigned long long* __restrict__ posw,
                                                   float* __restrict__ total,
                                                   float* __restrict__ possum){
  const int tid  = threadIdx.x;
  const int lane = tid & 63;
  const int w    = tid >> 6;                   // 0..3
  const int lr   = lane & 15, lk = lane >> 4;
  const int bid = (int)blockIdx.x;
  const int cb = (bid & 7) * 8 + ((bid >> 3) & 7);  // 0..63 (r3-verified swizzle)
  const int rb = bid >> 6;                          // 0..31
  const int i0 = rb << 7, n0 = cb << 7;
  const char* ctrB = (const char*)ctr;

  // ---- A fragments: contiguous 1KB per wave-load (fragment-major, r11)
  bf16x8 a[2][8];
  #pragma unroll
  for (int rt = 0; rt < 2; ++rt){
    const char* gbase = ctrB + ((size_t)((i0 >> 4) + (w << 1) + rt) << 13);
    #pragma unroll
    for (int ks = 0; ks < 8; ++ks)
      a[rt][ks] = *(const bf16x8*)(gbase + (ks << 10) + (lane << 4));
  }

  const int rowb = i0 + (w << 5) + (lk << 2);  // + rt*16 + q = this lane's rows
  float tot[2][4], pos[2][4];
  #pragma unroll
  for (int rt = 0; rt < 2; ++rt)
    #pragma unroll
    for (int q = 0; q < 4; ++q){ tot[rt][q] = 0.f; pos[rt][q] = 0.f; }

  #pragma unroll
  for (int h = 0; h < 2; ++h){
    // pos bits for this 64-col half (r6/r11-verified packing)
    const int widx = ((n0 & 4095) >> 6) + h;
    unsigned pbits = 0;
    #pragma unroll
    for (int rt = 0; rt < 2; ++rt)
      #pragma unroll
      for (int q = 0; q < 4; ++q){
        unsigned long long wv = posw[(size_t)(rowb + (rt << 4) + q) * 64 + widx];
        unsigned m4 = (unsigned)((wv >> lr) & 1ull)
                    | ((unsigned)((wv >> (16 + lr)) & 1ull) << 1)
                    | ((unsigned)((wv >> (32 + lr)) & 1ull) << 2)
                    | ((unsigned)((wv >> (48 + lr)) & 1ull) << 3);
        pbits |= m4 << (((rt << 2) + q) << 2);
      }

    #pragma unroll
    for (int ng = 0; ng < 4; ++ng){
      // B fragments straight from global: contiguous 1KB wave-bursts
      const char* bbase = ctrB + ((size_t)((n0 >> 4) + (h << 2) + ng) << 13);
      f32x4 acc0 = {0.f, 0.f, 0.f, 0.f};
      f32x4 acc1 = {0.f, 0.f, 0.f, 0.f};
      #pragma unroll
      for (int ks = 0; ks < 8; ++ks){
        bf16x8 b = *(const bf16x8*)(bbase + (ks << 10) + (lane << 4));
        acc0 = __builtin_amdgcn_mfma_f32_16x16x32_bf16(a[0][ks], b, acc0, 0, 0, 0);
        acc1 = __builtin_amdgcn_mfma_f32_16x16x32_bf16(a[1][ks], b, acc1, 0, 0, 0);
      }
      const int gcol = n0 + (h << 6) + (ng << 4) + lr;
      #pragma unroll
      for (int q = 0; q < 4; ++q){
        float e0 = fast_exp2(acc0[q] * EXP2SC);
        e0 = ((rowb + q) == gcol) ? 0.f : e0;
        tot[0][q] += e0;
        if ((pbits >> ((q << 2) + ng)) & 1u) pos[0][q] += e0;
        float e1 = fast_exp2(acc1[q] * EXP2SC);
        e1 = ((rowb + 16 + q) == gcol) ? 0.f : e1;
        tot[1][q] += e1;
        if ((pbits >> (((4 + q) << 2) + ng)) & 1u) pos[1][q] += e1;
      }
    }
  }

  // ---- reduce across lr (16 lanes) and one atomic pair per row ----
  #pragma unroll
  for (int rt = 0; rt < 2; ++rt){
    #pragma unroll
    for (int q = 0; q < 4; ++q){
      float v = tot[rt][q], u = pos[rt][q];
      v += __shfl_xor(v, 1); u += __shfl_xor(u, 1);
      v += __shfl_xor(v, 2); u += __shfl_xor(u, 2);
      v += __shfl_xor(v, 4); u += __shfl_xor(u, 4);
      v += __shfl_xor(v, 8); u += __shfl_xor(u, 8);
      if (lr == 0){
        int grow = rowb + (rt << 4) + q;
        atomicAdd(&total[grow], v);
        if (u != 0.f) atomicAdd(&possum[grow], u);
      }
    }
  }
}

// ---------------- kernel 5: finalize loss ----------------
__global__ __launch_bounds__(1024) void fin_kernel(const float* __restrict__ possum,
                                                   const float* __restrict__ total,
                                                   const int* __restrict__ poscnt,
                                                   const int* __restrict__ scnt,
                                                   float* __restrict__ out){
  int tid = threadIdx.x;
  float ls = 0.f, hc = 0.f;
  #pragma unroll
  for (int k = 0; k < 4; ++k){
    int i = k * 1024 + tid;
    int pii = (scnt[i] > 0) ? 1 : 0;
    int pm = 2 * poscnt[i] - pii;        // pos_m row count (self col removed)
    if (pm > 0){
      float ps = possum[i];
      float neg = total[i] - ps;
      ls += logf((ps + neg + 1e-8f) / ps);
      hc += 1.f;
    }
  }
  ls += __shfl_xor(ls, 1);  ls += __shfl_xor(ls, 2);  ls += __shfl_xor(ls, 4);
  ls += __shfl_xor(ls, 8);  ls += __shfl_xor(ls, 16); ls += __shfl_xor(ls, 32);
  hc += __shfl_xor(hc, 1);  hc += __shfl_xor(hc, 2);  hc += __shfl_xor(hc, 4);
  hc += __shfl_xor(hc, 8);  hc += __shfl_xor(hc, 16); hc += __shfl_xor(hc, 32);
  __shared__ float sl[16], sh[16];
  if ((tid & 63) == 0){ sl[tid >> 6] = ls; sh[tid >> 6] = hc; }
  __syncthreads();
  if (tid == 0){
    float S = 0.f, H = 0.f;
    #pragma unroll
    for (int w2 = 0; w2 < 16; ++w2){ S += sl[w2]; H += sh[w2]; }
    out[0] = S / fmaxf(H, 1.f);
  }
}

extern "C" void kernel_launch(void* const* d_in, const int* in_sizes, int n_in,
                              void* d_out, int out_size, void* d_ws, size_t ws_size,
                              hipStream_t stream){
  (void)in_sizes; (void)n_in; (void)out_size; (void)ws_size;
  const float* feat   = (const float*)d_in[0];
  const float* labels = (const float*)d_in[1];
  float* out = (float*)d_out;
  char* ws = (char*)d_ws;
  unsigned short* ctr       = (unsigned short*)(ws);               // 4,194,304 B
  unsigned long long* posw  = (unsigned long long*)(ws + 4194304); // 2,097,152 B
  ulonglong2* bits          = (ulonglong2*)(ws + 6291456);         //    65,536 B
  int* scnt                 = (int*)(ws + 6356992);                //    16,384 B
  float* possum             = (float*)(ws + 6373376);              //    16,384 B
  float* total              = (float*)(ws + 6389760);              //    16,384 B
  int* poscnt               = (int*)(ws + 6406144);                //    16,384 B

  hipLaunchKernelGGL(pack_kernel, dim3(16),   dim3(256),  0, stream, labels, bits, scnt, possum, total, poscnt);
  hipLaunchKernelGGL(conv_kernel, dim3(1024), dim3(256),  0, stream, feat, ctr);
  hipLaunchKernelGGL(pos_kernel,  dim3(4096), dim3(256),  0, stream, bits, scnt, posw, poscnt);
  hipLaunchKernelGGL(gemm_kernel, dim3(2048), dim3(256),  0, stream, ctr, posw, total, possum);
  hipLaunchKernelGGL(fin_kernel,  dim3(1),    dim3(1024), 0, stream, possum, total, poscnt, scnt, out);
}

// Round 14
// 75.368 us; speedup vs baseline: 1.1187x; 1.1187x over previous
//
#include <hip/hip_runtime.h>

#define B_ 4096
#define D_ 256
#define N_ 8192
// log2(e)/0.07
#define EXP2SC 20.60992915555662f

typedef float f32x4 __attribute__((ext_vector_type(4)));
typedef __bf16 bf16x8 __attribute__((ext_vector_type(8)));

__device__ __forceinline__ float fast_exp2(float x){
#if __has_builtin(__builtin_amdgcn_exp2f)
  return __builtin_amdgcn_exp2f(x);
#else
  return exp2f(x);
#endif
}

__device__ __forceinline__ unsigned short f2bf(float x){
  unsigned int u = __float_as_uint(x);
  unsigned int r = (u + 0x7fffu + ((u >> 16) & 1u)) >> 16;
  return (unsigned short)r;
}

// ------- kernel 1: pack labels + zero accumulators (r12-verified) -------
__global__ __launch_bounds__(256) void pack_kernel(const float* __restrict__ labels,
                                                   ulonglong2* __restrict__ bits,
                                                   int* __restrict__ scnt,
                                                   float* __restrict__ possum,
                                                   float* __restrict__ total,
                                                   int* __restrict__ poscnt){
  int i = blockIdx.x * 256 + threadIdx.x;      // 0..4095
  possum[i] = 0.f; total[i] = 0.f; poscnt[i] = 0;
  const float* L = labels + (size_t)i * 80;
  unsigned long long lo = 0ull, hi = 0ull;
  #pragma unroll
  for (int c = 0; c < 64; ++c) lo |= (L[c] > 0.5f) ? (1ull << c) : 0ull;
  #pragma unroll
  for (int c = 64; c < 80; ++c) hi |= (L[c] > 0.5f) ? (1ull << (c - 64)) : 0ull;
  bits[i] = make_ulonglong2(lo, hi);
  scnt[i] = __popcll(lo) + __popcll(hi);
}

// ------- kernel 2: f32 features -> bf16 contrast, FRAGMENT-MAJOR layout -------
// logical contrast[v*B + b][d] = f[b][v][d]; stored at (bytes)
// FM(row, c16) = (row>>4)<<13 | (c16>>2)<<10 | (c16&3)<<8 | (row&15)<<4
// so a wave's MFMA-fragment load is one contiguous 1KB burst. (r11-verified)
__global__ __launch_bounds__(256) void conv_kernel(const float* __restrict__ f,
                                                   unsigned short* __restrict__ ctr){
  int t = blockIdx.x * 256 + threadIdx.x;      // 0..262143, 8 elems each
  int row = t >> 5;                            // 0..8191
  int c   = t & 31;                            // 16B chunk 0..31
  int v = row >> 12, b = row & 4095;
  const float* src = f + ((((size_t)b << 1) + v) << 8) + (c << 3);
  float4 a = *(const float4*)src;
  float4 cc = *(const float4*)(src + 4);
  uint4 o;
  o.x = (unsigned)f2bf(a.x)  | ((unsigned)f2bf(a.y)  << 16);
  o.y = (unsigned)f2bf(a.z)  | ((unsigned)f2bf(a.w)  << 16);
  o.z = (unsigned)f2bf(cc.x) | ((unsigned)f2bf(cc.y) << 16);
  o.w = (unsigned)f2bf(cc.z) | ((unsigned)f2bf(cc.w) << 16);
  size_t oaddr = ((size_t)(row >> 4) << 13) + ((size_t)(c >> 2) << 10)
               + ((size_t)(c & 3) << 8) + ((size_t)(row & 15) << 4);
  *(uint4*)((char*)ctr + oaddr) = o;
}

// ------ kernel 3: Jaccard pos bitmask + fused per-row popcount ------
__global__ __launch_bounds__(256) void pos_kernel(const ulonglong2* __restrict__ bits,
                                                  const int* __restrict__ scnt,
                                                  unsigned long long* __restrict__ posw,
                                                  int* __restrict__ poscnt){
  __shared__ unsigned long long rbl[16], rbh[16];
  __shared__ int rs_sh[16];
  int tid = threadIdx.x;
  int bid = blockIdx.x;
  int i0 = (bid >> 4) << 4;                   // row group base
  int jm = ((bid & 15) << 8) + tid;           // this thread's column
  if (tid < 16){
    ulonglong2 bb = bits[i0 + tid];
    rbl[tid] = bb.x; rbh[tid] = bb.y;
    rs_sh[tid] = scnt[i0 + tid];
  }
  __syncthreads();
  ulonglong2 bj = bits[jm];
  int sj = scnt[jm];
  int lane = tid & 63;
  int wword = ((bid & 15) << 2) + (tid >> 6); // jm >> 6
  #pragma unroll
  for (int r = 0; r < 16; ++r){
    int inter = __popcll(rbl[r] & bj.x) + __popcll(rbh[r] & bj.y);
    int uni = rs_sh[r] + sj - inter;
    bool hit = false;
    if (2 * inter >= uni){                     // integer prefilter (superset)
      float sim = (float)inter / ((float)uni + 1e-6f);
      hit = (sim >= 0.5f);
    }
    unsigned long long m = __ballot(hit);
    if (lane == 0){
      posw[(size_t)(i0 + r) * 64 + wword] = m;
      if (m) atomicAdd(&poscnt[i0 + r], __popcll(m));  // sparse: ~2-3 hits/row
    }
  }
}

// ---- kernel 4: fused GEMM, fragment-major, counted-vmcnt 8-phase (T3+T4) ----
// 256 thr / 4 waves, tile 128x128, grid 2048, r3-verified swizzle.
// Full 64KB B-panel LDS; ALL 16 stage issues up-front (2/wave/phase, in
// program order); phase k waits s_waitcnt vmcnt(14-2k) + raw s_barrier ->
// later phases' loads stay in flight across barriers (m218 mechanism).
// A/pw loads complete (vmcnt(0)) BEFORE stage issues so counts are exact.
#define GLDS16(g, l) __builtin_amdgcn_global_load_lds( \
    (const __attribute__((address_space(1))) unsigned int*)(unsigned long long)(uintptr_t)(g), \
    (__attribute__((address_space(3))) unsigned int*)(unsigned int)(uintptr_t)(l), 16, 0, 0)

__global__ __launch_bounds__(256) void gemm_kernel(const unsigned short* __restrict__ ctr,
                                                   const unsigned long long* __restrict__ posw,
                                                   float* __restrict__ total,
                                                   float* __restrict__ possum){
  __shared__ __align__(16) char Bl[65536];     // 8 col-groups x 8KB, fm order
  const int tid  = threadIdx.x;
  const int lane = tid & 63;
  const int w    = tid >> 6;                   // 0..3
  const int lr   = lane & 15, lk = lane >> 4;
  const int bid = (int)blockIdx.x;
  const int cb = (bid & 7) * 8 + ((bid >> 3) & 7);  // 0..63 (r3-verified swizzle)
  const int rb = bid >> 6;                          // 0..31
  const int i0 = rb << 7, n0 = cb << 7;
  const char* ctrB = (const char*)ctr;

  // ---- A fragments: contiguous 1KB per wave-load (fragment-major, r11)
  bf16x8 a[2][8];
  #pragma unroll
  for (int rt = 0; rt < 2; ++rt){
    const char* gbase = ctrB + ((size_t)((i0 >> 4) + (w << 1) + rt) << 13);
    #pragma unroll
    for (int ks = 0; ks < 8; ++ks)
      a[rt][ks] = *(const bf16x8*)(gbase + (ks << 10) + (lane << 4));
  }

  const int rowb = i0 + (w << 5) + (lk << 2);  // + rt*16 + q = this lane's rows

  // ---- pos bits for both 64-col halves (r6/r11-verified packing)
  unsigned pb0 = 0, pb1 = 0;
  #pragma unroll
  for (int h = 0; h < 2; ++h){
    const int widx = ((n0 & 4095) >> 6) + h;
    unsigned pbits = 0;
    #pragma unroll
    for (int rt = 0; rt < 2; ++rt)
      #pragma unroll
      for (int q = 0; q < 4; ++q){
        unsigned long long wv = posw[(size_t)(rowb + (rt << 4) + q) * 64 + widx];
        unsigned m4 = (unsigned)((wv >> lr) & 1ull)
                    | ((unsigned)((wv >> (16 + lr)) & 1ull) << 1)
                    | ((unsigned)((wv >> (32 + lr)) & 1ull) << 2)
                    | ((unsigned)((wv >> (48 + lr)) & 1ull) << 3);
        pbits |= m4 << (((rt << 2) + q) << 2);
      }
    if (h) pb1 = pbits; else pb0 = pbits;
  }

  // A + pw fully landed; vmcnt clean before stage issues (exact counting)
  asm volatile("s_waitcnt vmcnt(0)" ::: "memory");

  // ---- ALL stage issues up-front: phase k gets issues 2k, 2k+1 (per wave)
  #pragma unroll
  for (int k = 0; k < 8; ++k){
    const char* src_ = ctrB + ((size_t)((n0 >> 4) + k) << 13) + (w << 11);
    GLDS16(src_ + (lane << 4),        Bl + (k << 13) + (w << 11));
    GLDS16(src_ + 1024 + (lane << 4), Bl + (k << 13) + (w << 11) + 1024);
  }

  float tot[2][4], pos[2][4];
  #pragma unroll
  for (int rt = 0; rt < 2; ++rt)
    #pragma unroll
    for (int q = 0; q < 4; ++q){ tot[rt][q] = 0.f; pos[rt][q] = 0.f; }

  #define PHASE(K, VM) do { \
    asm volatile("s_waitcnt vmcnt(" VM ")" ::: "memory"); \
    __builtin_amdgcn_s_barrier(); \
    const char* bbase = Bl + ((K) << 13); \
    f32x4 acc0 = {0.f,0.f,0.f,0.f}; \
    f32x4 acc1 = {0.f,0.f,0.f,0.f}; \
    _Pragma("unroll") \
    for (int ks = 0; ks < 8; ++ks){ \
      bf16x8 b = *(const bf16x8*)(bbase + (ks << 10) + (lane << 4)); \
      acc0 = __builtin_amdgcn_mfma_f32_16x16x32_bf16(a[0][ks], b, acc0, 0, 0, 0); \
      acc1 = __builtin_amdgcn_mfma_f32_16x16x32_bf16(a[1][ks], b, acc1, 0, 0, 0); \
    } \
    const int gcol = n0 + ((K) << 4) + lr; \
    const unsigned pb = ((K) >= 4) ? pb1 : pb0; \
    _Pragma("unroll") \
    for (int q = 0; q < 4; ++q){ \
      float e0 = fast_exp2(acc0[q] * EXP2SC); \
      e0 = ((rowb + q) == gcol) ? 0.f : e0; \
      tot[0][q] += e0; \
      if ((pb >> ((q << 2) + ((K) & 3))) & 1u) pos[0][q] += e0; \
      float e1 = fast_exp2(acc1[q] * EXP2SC); \
      e1 = ((rowb + 16 + q) == gcol) ? 0.f : e1; \
      tot[1][q] += e1; \
      if ((pb >> (((4 + q) << 2) + ((K) & 3))) & 1u) pos[1][q] += e1; \
    } \
  } while(0)

  PHASE(0, "14");
  PHASE(1, "12");
  PHASE(2, "10");
  PHASE(3, "8");
  PHASE(4, "6");
  PHASE(5, "4");
  PHASE(6, "2");
  PHASE(7, "0");
  #undef PHASE

  // ---- reduce across lr (16 lanes) and one atomic pair per row ----
  #pragma unroll
  for (int rt = 0; rt < 2; ++rt){
    #pragma unroll
    for (int q = 0; q < 4; ++q){
      float v = tot[rt][q], u = pos[rt][q];
      v += __shfl_xor(v, 1); u += __shfl_xor(u, 1);
      v += __shfl_xor(v, 2); u += __shfl_xor(u, 2);
      v += __shfl_xor(v, 4); u += __shfl_xor(u, 4);
      v += __shfl_xor(v, 8); u += __shfl_xor(u, 8);
      if (lr == 0){
        int grow = rowb + (rt << 4) + q;
        atomicAdd(&total[grow], v);
        if (u != 0.f) atomicAdd(&possum[grow], u);
      }
    }
  }
}

// ---------------- kernel 5: finalize loss ----------------
__global__ __launch_bounds__(1024) void fin_kernel(const float* __restrict__ possum,
                                                   const float* __restrict__ total,
                                                   const int* __restrict__ poscnt,
                                                   const int* __restrict__ scnt,
                                                   float* __restrict__ out){
  int tid = threadIdx.x;
  float ls = 0.f, hc = 0.f;
  #pragma unroll
  for (int k = 0; k < 4; ++k){
    int i = k * 1024 + tid;
    int pii = (scnt[i] > 0) ? 1 : 0;
    int pm = 2 * poscnt[i] - pii;        // pos_m row count (self col removed)
    if (pm > 0){
      float ps = possum[i];
      float neg = total[i] - ps;
      ls += logf((ps + neg + 1e-8f) / ps);
      hc += 1.f;
    }
  }
  ls += __shfl_xor(ls, 1);  ls += __shfl_xor(ls, 2);  ls += __shfl_xor(ls, 4);
  ls += __shfl_xor(ls, 8);  ls += __shfl_xor(ls, 16); ls += __shfl_xor(ls, 32);
  hc += __shfl_xor(hc, 1);  hc += __shfl_xor(hc, 2);  hc += __shfl_xor(hc, 4);
  hc += __shfl_xor(hc, 8);  hc += __shfl_xor(hc, 16); hc += __shfl_xor(hc, 32);
  __shared__ float sl[16], sh[16];
  if ((tid & 63) == 0){ sl[tid >> 6] = ls; sh[tid >> 6] = hc; }
  __syncthreads();
  if (tid == 0){
    float S = 0.f, H = 0.f;
    #pragma unroll
    for (int w2 = 0; w2 < 16; ++w2){ S += sl[w2]; H += sh[w2]; }
    out[0] = S / fmaxf(H, 1.f);
  }
}

extern "C" void kernel_launch(void* const* d_in, const int* in_sizes, int n_in,
                              void* d_out, int out_size, void* d_ws, size_t ws_size,
                              hipStream_t stream){
  (void)in_sizes; (void)n_in; (void)out_size; (void)ws_size;
  const float* feat   = (const float*)d_in[0];
  const float* labels = (const float*)d_in[1];
  float* out = (float*)d_out;
  char* ws = (char*)d_ws;
  unsigned short* ctr       = (unsigned short*)(ws);               // 4,194,304 B
  unsigned long long* posw  = (unsigned long long*)(ws + 4194304); // 2,097,152 B
  ulonglong2* bits          = (ulonglong2*)(ws + 6291456);         //    65,536 B
  int* scnt                 = (int*)(ws + 6356992);                //    16,384 B
  float* possum             = (float*)(ws + 6373376);              //    16,384 B
  float* total              = (float*)(ws + 6389760);              //    16,384 B
  int* poscnt               = (int*)(ws + 6406144);                //    16,384 B

  hipLaunchKernelGGL(pack_kernel, dim3(16),   dim3(256),  0, stream, labels, bits, scnt, possum, total, poscnt);
  hipLaunchKernelGGL(conv_kernel, dim3(1024), dim3(256),  0, stream, feat, ctr);
  hipLaunchKernelGGL(pos_kernel,  dim3(4096), dim3(256),  0, stream, bits, scnt, posw, poscnt);
  hipLaunchKernelGGL(gemm_kernel, dim3(2048), dim3(256),  0, stream, ctr, posw, total, possum);
  hipLaunchKernelGGL(fin_kernel,  dim3(1),    dim3(1024), 0, stream, possum, total, poscnt, scnt, out);
}

// Round 15
// 70.619 us; speedup vs baseline: 1.1939x; 1.0672x over previous
//
#include <hip/hip_runtime.h>

#define B_ 4096
#define D_ 256
#define N_ 8192
// log2(e)/0.07
#define EXP2SC 20.60992915555662f

typedef float f32x4 __attribute__((ext_vector_type(4)));
typedef __bf16 bf16x8 __attribute__((ext_vector_type(8)));

__device__ __forceinline__ float fast_exp2(float x){
#if __has_builtin(__builtin_amdgcn_exp2f)
  return __builtin_amdgcn_exp2f(x);
#else
  return exp2f(x);
#endif
}

__device__ __forceinline__ unsigned short f2bf(float x){
  unsigned int u = __float_as_uint(x);
  unsigned int r = (u + 0x7fffu + ((u >> 16) & 1u)) >> 16;
  return (unsigned short)r;
}

// --- kernel 1: merged prep = pack labels + zero accums (blocks 0..15)
//     and f32->bf16 fragment-major convert (blocks 16..1039) ---
// FM(row, c16) = (row>>4)<<13 | (c16>>2)<<10 | (c16&3)<<8 | (row&15)<<4
// (both halves individually r12/r11-verified)
__global__ __launch_bounds__(256) void prep_kernel(const float* __restrict__ labels,
                                                   const float* __restrict__ f,
                                                   ulonglong2* __restrict__ bits,
                                                   int* __restrict__ scnt,
                                                   unsigned short* __restrict__ ctr,
                                                   float* __restrict__ possum,
                                                   float* __restrict__ total,
                                                   int* __restrict__ poscnt){
  int bid = blockIdx.x;
  int tid = threadIdx.x;
  if (bid < 16){
    int i = bid * 256 + tid;                   // 0..4095
    possum[i] = 0.f; total[i] = 0.f; poscnt[i] = 0;
    const float* L = labels + (size_t)i * 80;
    unsigned long long lo = 0ull, hi = 0ull;
    #pragma unroll
    for (int c = 0; c < 64; ++c) lo |= (L[c] > 0.5f) ? (1ull << c) : 0ull;
    #pragma unroll
    for (int c = 64; c < 80; ++c) hi |= (L[c] > 0.5f) ? (1ull << (c - 64)) : 0ull;
    bits[i] = make_ulonglong2(lo, hi);
    scnt[i] = __popcll(lo) + __popcll(hi);
  } else {
    int t = (bid - 16) * 256 + tid;            // 0..262143, 8 elems each
    int row = t >> 5;                          // 0..8191
    int c   = t & 31;                          // 16B chunk 0..31
    int v = row >> 12, b = row & 4095;
    const float* src = f + ((((size_t)b << 1) + v) << 8) + (c << 3);
    float4 a = *(const float4*)src;
    float4 cc = *(const float4*)(src + 4);
    uint4 o;
    o.x = (unsigned)f2bf(a.x)  | ((unsigned)f2bf(a.y)  << 16);
    o.y = (unsigned)f2bf(a.z)  | ((unsigned)f2bf(a.w)  << 16);
    o.z = (unsigned)f2bf(cc.x) | ((unsigned)f2bf(cc.y) << 16);
    o.w = (unsigned)f2bf(cc.z) | ((unsigned)f2bf(cc.w) << 16);
    size_t oaddr = ((size_t)(row >> 4) << 13) + ((size_t)(c >> 2) << 10)
                 + ((size_t)(c & 3) << 8) + ((size_t)(row & 15) << 4);
    *(uint4*)((char*)ctr + oaddr) = o;
  }
}

// ------ kernel 2: Jaccard pos bitmask + fused per-row popcount ------
__global__ __launch_bounds__(256) void pos_kernel(const ulonglong2* __restrict__ bits,
                                                  const int* __restrict__ scnt,
                                                  unsigned long long* __restrict__ posw,
                                                  int* __restrict__ poscnt){
  __shared__ unsigned long long rbl[16], rbh[16];
  __shared__ int rs_sh[16];
  int tid = threadIdx.x;
  int bid = blockIdx.x;
  int i0 = (bid >> 4) << 4;                   // row group base
  int jm = ((bid & 15) << 8) + tid;           // this thread's column
  if (tid < 16){
    ulonglong2 bb = bits[i0 + tid];
    rbl[tid] = bb.x; rbh[tid] = bb.y;
    rs_sh[tid] = scnt[i0 + tid];
  }
  __syncthreads();
  ulonglong2 bj = bits[jm];
  int sj = scnt[jm];
  int lane = tid & 63;
  int wword = ((bid & 15) << 2) + (tid >> 6); // jm >> 6
  #pragma unroll
  for (int r = 0; r < 16; ++r){
    int inter = __popcll(rbl[r] & bj.x) + __popcll(rbh[r] & bj.y);
    int uni = rs_sh[r] + sj - inter;
    bool hit = false;
    if (2 * inter >= uni){                     // integer prefilter (superset)
      float sim = (float)inter / ((float)uni + 1e-6f);
      hit = (sim >= 0.5f);
    }
    unsigned long long m = __ballot(hit);
    if (lane == 0){
      posw[(size_t)(i0 + r) * 64 + wword] = m;
      if (m) atomicAdd(&poscnt[i0 + r], __popcll(m));  // sparse: ~2-3 hits/row
    }
  }
}

// ---- kernel 3: fused GEMM on fragment-major ctr (r11-EXACT structure) ----
// 256 thr / 4 waves, tile 128x128, grid 2048, r3-verified swizzle, 3-barrier
// shape. A: 16 contiguous-1KB wave loads -> regs. B: per 64-col half, one
// linear 32KB global_load_lds copy; fragment ds_reads lane-linear. 44.6 us.
#define GLDS16(g, l) __builtin_amdgcn_global_load_lds( \
    (const __attribute__((address_space(1))) unsigned int*)(unsigned long long)(uintptr_t)(g), \
    (__attribute__((address_space(3))) unsigned int*)(unsigned int)(uintptr_t)(l), 16, 0, 0)

__global__ __launch_bounds__(256) void gemm_kernel(const unsigned short* __restrict__ ctr,
                                                   const unsigned long long* __restrict__ posw,
                                                   float* __restrict__ total,
                                                   float* __restrict__ possum){
  __shared__ __align__(16) char Bl[32768];     // 4 col-groups x 8KB, fm order
  const int tid  = threadIdx.x;
  const int lane = tid & 63;
  const int w    = tid >> 6;                   // 0..3
  const int lr   = lane & 15, lk = lane >> 4;
  const int bid = (int)blockIdx.x;
  const int cb = (bid & 7) * 8 + ((bid >> 3) & 7);  // 0..63 (r3-verified swizzle)
  const int rb = bid >> 6;                          // 0..31
  const int i0 = rb << 7, n0 = cb << 7;
  const char* ctrB = (const char*)ctr;

  // stage half H: 4 col-groups = contiguous 32KB, straight linear copy.
  #define STAGEH(H) do { \
    const char* src_ = ctrB + ((size_t)((n0 >> 4) + ((H) << 2)) << 13); \
    _Pragma("unroll") \
    for (int is = 0; is < 8; ++is){ \
      int off_ = (is << 12) + (w << 10);       /* wave-uniform */ \
      GLDS16(src_ + off_ + (lane << 4), Bl + off_); \
    } } while(0)

  // ---- A fragments: contiguous 1KB per wave-load (fragment-major)
  bf16x8 a[2][8];
  #pragma unroll
  for (int rt = 0; rt < 2; ++rt){
    const char* gbase = ctrB + ((size_t)((i0 >> 4) + (w << 1) + rt) << 13);
    #pragma unroll
    for (int ks = 0; ks < 8; ++ks)
      a[rt][ks] = *(const bf16x8*)(gbase + (ks << 10) + (lane << 4));
  }

  const int rowb = i0 + (w << 5) + (lk << 2);  // + rt*16 + q = this lane's rows
  float tot[2][4], pos[2][4];
  #pragma unroll
  for (int rt = 0; rt < 2; ++rt)
    #pragma unroll
    for (int q = 0; q < 4; ++q){ tot[rt][q] = 0.f; pos[rt][q] = 0.f; }

  STAGEH(0);
  __syncthreads();
  #pragma unroll
  for (int h = 0; h < 2; ++h){
    if (h){
      __syncthreads();                         // all reads of half0 done
      STAGEH(1);
      __syncthreads();
    }
    // pos bits for this 64-col half (r6/r11-verified packing)
    const int widx = ((n0 & 4095) >> 6) + h;
    unsigned pbits = 0;
    #pragma unroll
    for (int rt = 0; rt < 2; ++rt)
      #pragma unroll
      for (int q = 0; q < 4; ++q){
        unsigned long long wv = posw[(size_t)(rowb + (rt << 4) + q) * 64 + widx];
        unsigned m4 = (unsigned)((wv >> lr) & 1ull)
                    | ((unsigned)((wv >> (16 + lr)) & 1ull) << 1)
                    | ((unsigned)((wv >> (32 + lr)) & 1ull) << 2)
                    | ((unsigned)((wv >> (48 + lr)) & 1ull) << 3);
        pbits |= m4 << (((rt << 2) + q) << 2);
      }

    #pragma unroll
    for (int ng = 0; ng < 4; ++ng){
      const char* bbase = Bl + (ng << 13);     // 8KB per col-group
      f32x4 acc0 = {0.f, 0.f, 0.f, 0.f};
      f32x4 acc1 = {0.f, 0.f, 0.f, 0.f};
      #pragma unroll
      for (int ks = 0; ks < 8; ++ks){
        bf16x8 b = *(const bf16x8*)(bbase + (ks << 10) + (lane << 4));
        acc0 = __builtin_amdgcn_mfma_f32_16x16x32_bf16(a[0][ks], b, acc0, 0, 0, 0);
        acc1 = __builtin_amdgcn_mfma_f32_16x16x32_bf16(a[1][ks], b, acc1, 0, 0, 0);
      }
      const int gcol = n0 + (h << 6) + (ng << 4) + lr;
      #pragma unroll
      for (int q = 0; q < 4; ++q){
        float e0 = fast_exp2(acc0[q] * EXP2SC);
        e0 = ((rowb + q) == gcol) ? 0.f : e0;
        tot[0][q] += e0;
        if ((pbits >> ((q << 2) + ng)) & 1u) pos[0][q] += e0;
        float e1 = fast_exp2(acc1[q] * EXP2SC);
        e1 = ((rowb + 16 + q) == gcol) ? 0.f : e1;
        tot[1][q] += e1;
        if ((pbits >> (((4 + q) << 2) + ng)) & 1u) pos[1][q] += e1;
      }
    }
  }

  // ---- reduce across lr (16 lanes) and one atomic pair per row ----
  #pragma unroll
  for (int rt = 0; rt < 2; ++rt){
    #pragma unroll
    for (int q = 0; q < 4; ++q){
      float v = tot[rt][q], u = pos[rt][q];
      v += __shfl_xor(v, 1); u += __shfl_xor(u, 1);
      v += __shfl_xor(v, 2); u += __shfl_xor(u, 2);
      v += __shfl_xor(v, 4); u += __shfl_xor(u, 4);
      v += __shfl_xor(v, 8); u += __shfl_xor(u, 8);
      if (lr == 0){
        int grow = rowb + (rt << 4) + q;
        atomicAdd(&total[grow], v);
        if (u != 0.f) atomicAdd(&possum[grow], u);
      }
    }
  }
  #undef STAGEH
}

// ---------------- kernel 4: finalize loss ----------------
__global__ __launch_bounds__(1024) void fin_kernel(const float* __restrict__ possum,
                                                   const float* __restrict__ total,
                                                   const int* __restrict__ poscnt,
                                                   const int* __restrict__ scnt,
                                                   float* __restrict__ out){
  int tid = threadIdx.x;
  float ls = 0.f, hc = 0.f;
  #pragma unroll
  for (int k = 0; k < 4; ++k){
    int i = k * 1024 + tid;
    int pii = (scnt[i] > 0) ? 1 : 0;
    int pm = 2 * poscnt[i] - pii;        // pos_m row count (self col removed)
    if (pm > 0){
      float ps = possum[i];
      float neg = total[i] - ps;
      ls += logf((ps + neg + 1e-8f) / ps);
      hc += 1.f;
    }
  }
  ls += __shfl_xor(ls, 1);  ls += __shfl_xor(ls, 2);  ls += __shfl_xor(ls, 4);
  ls += __shfl_xor(ls, 8);  ls += __shfl_xor(ls, 16); ls += __shfl_xor(ls, 32);
  hc += __shfl_xor(hc, 1);  hc += __shfl_xor(hc, 2);  hc += __shfl_xor(hc, 4);
  hc += __shfl_xor(hc, 8);  hc += __shfl_xor(hc, 16); hc += __shfl_xor(hc, 32);
  __shared__ float sl[16], sh[16];
  if ((tid & 63) == 0){ sl[tid >> 6] = ls; sh[tid >> 6] = hc; }
  __syncthreads();
  if (tid == 0){
    float S = 0.f, H = 0.f;
    #pragma unroll
    for (int w2 = 0; w2 < 16; ++w2){ S += sl[w2]; H += sh[w2]; }
    out[0] = S / fmaxf(H, 1.f);
  }
}

extern "C" void kernel_launch(void* const* d_in, const int* in_sizes, int n_in,
                              void* d_out, int out_size, void* d_ws, size_t ws_size,
                              hipStream_t stream){
  (void)in_sizes; (void)n_in; (void)out_size; (void)ws_size;
  const float* feat   = (const float*)d_in[0];
  const float* labels = (const float*)d_in[1];
  float* out = (float*)d_out;
  char* ws = (char*)d_ws;
  unsigned short* ctr       = (unsigned short*)(ws);               // 4,194,304 B
  unsigned long long* posw  = (unsigned long long*)(ws + 4194304); // 2,097,152 B
  ulonglong2* bits          = (ulonglong2*)(ws + 6291456);         //    65,536 B
  int* scnt                 = (int*)(ws + 6356992);                //    16,384 B
  float* possum             = (float*)(ws + 6373376);              //    16,384 B
  float* total              = (float*)(ws + 6389760);              //    16,384 B
  int* poscnt               = (int*)(ws + 6406144);                //    16,384 B

  hipLaunchKernelGGL(prep_kernel, dim3(1040), dim3(256),  0, stream, labels, feat, bits, scnt, ctr, possum, total, poscnt);
  hipLaunchKernelGGL(pos_kernel,  dim3(4096), dim3(256),  0, stream, bits, scnt, posw, poscnt);
  hipLaunchKernelGGL(gemm_kernel, dim3(2048), dim3(256),  0, stream, ctr, posw, total, possum);
  hipLaunchKernelGGL(fin_kernel,  dim3(1),    dim3(1024), 0, stream, possum, total, poscnt, scnt, out);
}

// Round 16
// 58.132 us; speedup vs baseline: 1.4504x; 1.2148x over previous
//
#include <hip/hip_runtime.h>

#define B_ 4096
#define D_ 256
#define N_ 8192
// log2(e)/0.07
#define EXP2SC 20.60992915555662f

typedef float f32x4 __attribute__((ext_vector_type(4)));
typedef __bf16 bf16x8 __attribute__((ext_vector_type(8)));

__device__ __forceinline__ float fast_exp2(float x){
#if __has_builtin(__builtin_amdgcn_exp2f)
  return __builtin_amdgcn_exp2f(x);
#else
  return exp2f(x);
#endif
}

__device__ __forceinline__ unsigned short f2bf(float x){
  unsigned int u = __float_as_uint(x);
  unsigned int r = (u + 0x7fffu + ((u >> 16) & 1u)) >> 16;
  return (unsigned short)r;
}

// --- kernel 1: merged prep = pack labels + zero accums (blocks 0..15)
//     and f32->bf16 fragment-major convert (blocks 16..1039) --- (r15-verified)
__global__ __launch_bounds__(256) void prep_kernel(const float* __restrict__ labels,
                                                   const float* __restrict__ f,
                                                   ulonglong2* __restrict__ bits,
                                                   int* __restrict__ scnt,
                                                   unsigned short* __restrict__ ctr,
                                                   float* __restrict__ possum,
                                                   float* __restrict__ total,
                                                   int* __restrict__ poscnt){
  int bid = blockIdx.x;
  int tid = threadIdx.x;
  if (bid < 16){
    int i = bid * 256 + tid;                   // 0..4095
    possum[i] = 0.f; total[i] = 0.f; poscnt[i] = 0;
    const float* L = labels + (size_t)i * 80;
    unsigned long long lo = 0ull, hi = 0ull;
    #pragma unroll
    for (int c = 0; c < 64; ++c) lo |= (L[c] > 0.5f) ? (1ull << c) : 0ull;
    #pragma unroll
    for (int c = 64; c < 80; ++c) hi |= (L[c] > 0.5f) ? (1ull << (c - 64)) : 0ull;
    bits[i] = make_ulonglong2(lo, hi);
    scnt[i] = __popcll(lo) + __popcll(hi);
  } else {
    int t = (bid - 16) * 256 + tid;            // 0..262143, 8 elems each
    int row = t >> 5;                          // 0..8191
    int c   = t & 31;                          // 16B chunk 0..31
    int v = row >> 12, b = row & 4095;
    const float* src = f + ((((size_t)b << 1) + v) << 8) + (c << 3);
    float4 a = *(const float4*)src;
    float4 cc = *(const float4*)(src + 4);
    uint4 o;
    o.x = (unsigned)f2bf(a.x)  | ((unsigned)f2bf(a.y)  << 16);
    o.y = (unsigned)f2bf(a.z)  | ((unsigned)f2bf(a.w)  << 16);
    o.z = (unsigned)f2bf(cc.x) | ((unsigned)f2bf(cc.y) << 16);
    o.w = (unsigned)f2bf(cc.z) | ((unsigned)f2bf(cc.w) << 16);
    size_t oaddr = ((size_t)(row >> 4) << 13) + ((size_t)(c >> 2) << 10)
                 + ((size_t)(c & 3) << 8) + ((size_t)(row & 15) << 4);
    *(uint4*)((char*)ctr + oaddr) = o;
  }
}

// ------ kernel 2: Jaccard pos bitmask + fused per-row popcount ------
__global__ __launch_bounds__(256) void pos_kernel(const ulonglong2* __restrict__ bits,
                                                  const int* __restrict__ scnt,
                                                  unsigned long long* __restrict__ posw,
                                                  int* __restrict__ poscnt){
  __shared__ unsigned long long rbl[16], rbh[16];
  __shared__ int rs_sh[16];
  int tid = threadIdx.x;
  int bid = blockIdx.x;
  int i0 = (bid >> 4) << 4;                   // row group base
  int jm = ((bid & 15) << 8) + tid;           // this thread's column
  if (tid < 16){
    ulonglong2 bb = bits[i0 + tid];
    rbl[tid] = bb.x; rbh[tid] = bb.y;
    rs_sh[tid] = scnt[i0 + tid];
  }
  __syncthreads();
  ulonglong2 bj = bits[jm];
  int sj = scnt[jm];
  int lane = tid & 63;
  int wword = ((bid & 15) << 2) + (tid >> 6); // jm >> 6
  #pragma unroll
  for (int r = 0; r < 16; ++r){
    int inter = __popcll(rbl[r] & bj.x) + __popcll(rbh[r] & bj.y);
    int uni = rs_sh[r] + sj - inter;
    bool hit = false;
    if (2 * inter >= uni){                     // integer prefilter (superset)
      float sim = (float)inter / ((float)uni + 1e-6f);
      hit = (sim >= 0.5f);
    }
    unsigned long long m = __ballot(hit);
    if (lane == 0){
      posw[(size_t)(i0 + r) * 64 + wword] = m;
      if (m) atomicAdd(&poscnt[i0 + r], __popcll(m));  // sparse: ~2-3 hits/row
    }
  }
}

// ---- kernel 3: fused GEMM, fragment-major, SYMMETRY-HALVED left block ----
// r15-exact structure; grid 1552 = 1024 right-half tiles (cb 32..63, all rb)
// + 528 left-triangle tiles (rb <= cb < 32). Off-diagonal triangle tiles
// contribute BOTH row sums and column sums (e[i][j] = e[j][i]; pos matrix
// symmetric so the same pbits serve both). Diagonal tiles: row sums only.
#define GLDS16(g, l) __builtin_amdgcn_global_load_lds( \
    (const __attribute__((address_space(1))) unsigned int*)(unsigned long long)(uintptr_t)(g), \
    (__attribute__((address_space(3))) unsigned int*)(unsigned int)(uintptr_t)(l), 16, 0, 0)

__global__ __launch_bounds__(256) void gemm_kernel(const unsigned short* __restrict__ ctr,
                                                   const unsigned long long* __restrict__ posw,
                                                   float* __restrict__ total,
                                                   float* __restrict__ possum){
  __shared__ __align__(16) char Bl[32768];     // 4 col-groups x 8KB, fm order
  const int tid  = threadIdx.x;
  const int lane = tid & 63;
  const int w    = tid >> 6;                   // 0..3
  const int lr   = lane & 15, lk = lane >> 4;
  const int bid = (int)blockIdx.x;

  int rb, cb;
  bool doCol;
  if (bid < 1024){
    // right half: cols 4096..8191, r12-verified bijective XCD swizzle
    const int swz = (bid & 7) * 128 + (bid >> 3);
    rb = swz & 31; cb = 32 + (swz >> 5);
    doCol = false;
  } else {
    // left triangle: rb <= cb < 32; 528 = 8 x 66 bijective interleave
    int t0 = bid - 1024;                       // 0..527
    int t  = (t0 & 7) * 66 + (t0 >> 3);
    // S(r) = r*(65-r)/2 = #tiles with row < r; disc is a perfect square at
    // boundaries so sqrtf is exact there; integer fix-up for safety.
    int r = (int)((65.0f - sqrtf((float)(4225 - 8 * t))) * 0.5f);
    while ((r + 1) * (65 - (r + 1)) / 2 <= t) ++r;
    while (r * (65 - r) / 2 > t) --r;
    rb = r;
    cb = r + (t - r * (65 - r) / 2);
    doCol = (rb != cb);
  }
  const int i0 = rb << 7, n0 = cb << 7;
  const char* ctrB = (const char*)ctr;

  // stage half H: 4 col-groups = contiguous 32KB, straight linear copy.
  #define STAGEH(H) do { \
    const char* src_ = ctrB + ((size_t)((n0 >> 4) + ((H) << 2)) << 13); \
    _Pragma("unroll") \
    for (int is = 0; is < 8; ++is){ \
      int off_ = (is << 12) + (w << 10);       /* wave-uniform */ \
      GLDS16(src_ + off_ + (lane << 4), Bl + off_); \
    } } while(0)

  // ---- A fragments: contiguous 1KB per wave-load (fragment-major)
  bf16x8 a[2][8];
  #pragma unroll
  for (int rt = 0; rt < 2; ++rt){
    const char* gbase = ctrB + ((size_t)((i0 >> 4) + (w << 1) + rt) << 13);
    #pragma unroll
    for (int ks = 0; ks < 8; ++ks)
      a[rt][ks] = *(const bf16x8*)(gbase + (ks << 10) + (lane << 4));
  }

  const int rowb = i0 + (w << 5) + (lk << 2);  // + rt*16 + q = this lane's rows
  float tot[2][4], pos[2][4];
  #pragma unroll
  for (int rt = 0; rt < 2; ++rt)
    #pragma unroll
    for (int q = 0; q < 4; ++q){ tot[rt][q] = 0.f; pos[rt][q] = 0.f; }

  STAGEH(0);
  __syncthreads();
  #pragma unroll
  for (int h = 0; h < 2; ++h){
    if (h){
      __syncthreads();                         // all reads of half0 done
      STAGEH(1);
      __syncthreads();
    }
    // pos bits for this 64-col half (r6/r11-verified packing)
    const int widx = ((n0 & 4095) >> 6) + h;
    unsigned pbits = 0;
    #pragma unroll
    for (int rt = 0; rt < 2; ++rt)
      #pragma unroll
      for (int q = 0; q < 4; ++q){
        unsigned long long wv = posw[(size_t)(rowb + (rt << 4) + q) * 64 + widx];
        unsigned m4 = (unsigned)((wv >> lr) & 1ull)
                    | ((unsigned)((wv >> (16 + lr)) & 1ull) << 1)
                    | ((unsigned)((wv >> (32 + lr)) & 1ull) << 2)
                    | ((unsigned)((wv >> (48 + lr)) & 1ull) << 3);
        pbits |= m4 << (((rt << 2) + q) << 2);
      }

    #pragma unroll
    for (int ng = 0; ng < 4; ++ng){
      const char* bbase = Bl + (ng << 13);     // 8KB per col-group
      f32x4 acc0 = {0.f, 0.f, 0.f, 0.f};
      f32x4 acc1 = {0.f, 0.f, 0.f, 0.f};
      #pragma unroll
      for (int ks = 0; ks < 8; ++ks){
        bf16x8 b = *(const bf16x8*)(bbase + (ks << 10) + (lane << 4));
        acc0 = __builtin_amdgcn_mfma_f32_16x16x32_bf16(a[0][ks], b, acc0, 0, 0, 0);
        acc1 = __builtin_amdgcn_mfma_f32_16x16x32_bf16(a[1][ks], b, acc1, 0, 0, 0);
      }
      const int gcol = n0 + (h << 6) + (ng << 4) + lr;
      float ct = 0.f, cp = 0.f;                // column partials (this lane)
      #pragma unroll
      for (int q = 0; q < 4; ++q){
        float e0 = fast_exp2(acc0[q] * EXP2SC);
        e0 = ((rowb + q) == gcol) ? 0.f : e0;
        tot[0][q] += e0;
        bool b0 = (pbits >> ((q << 2) + ng)) & 1u;
        if (b0) pos[0][q] += e0;
        float e1 = fast_exp2(acc1[q] * EXP2SC);
        e1 = ((rowb + 16 + q) == gcol) ? 0.f : e1;
        tot[1][q] += e1;
        bool b1 = (pbits >> (((4 + q) << 2) + ng)) & 1u;
        if (b1) pos[1][q] += e1;
        if (doCol){
          ct += e0 + e1;
          cp += (b0 ? e0 : 0.f) + (b1 ? e1 : 0.f);
        }
      }
      if (doCol){
        // reduce across lk (rows this wave): lanes lk*16+lr, xor 16 & 32
        ct += __shfl_xor(ct, 16); cp += __shfl_xor(cp, 16);
        ct += __shfl_xor(ct, 32); cp += __shfl_xor(cp, 32);
        if (lk == 0){                          // one lane per column per wave
          atomicAdd(&total[gcol], ct);
          if (cp != 0.f) atomicAdd(&possum[gcol], cp);
        }
      }
    }
  }

  // ---- reduce across lr (16 lanes) and one atomic pair per row ----
  #pragma unroll
  for (int rt = 0; rt < 2; ++rt){
    #pragma unroll
    for (int q = 0; q < 4; ++q){
      float v = tot[rt][q], u = pos[rt][q];
      v += __shfl_xor(v, 1); u += __shfl_xor(u, 1);
      v += __shfl_xor(v, 2); u += __shfl_xor(u, 2);
      v += __shfl_xor(v, 4); u += __shfl_xor(u, 4);
      v += __shfl_xor(v, 8); u += __shfl_xor(u, 8);
      if (lr == 0){
        int grow = rowb + (rt << 4) + q;
        atomicAdd(&total[grow], v);
        if (u != 0.f) atomicAdd(&possum[grow], u);
      }
    }
  }
  #undef STAGEH
}

// ---------------- kernel 4: finalize loss ----------------
__global__ __launch_bounds__(1024) void fin_kernel(const float* __restrict__ possum,
                                                   const float* __restrict__ total,
                                                   const int* __restrict__ poscnt,
                                                   const int* __restrict__ scnt,
                                                   float* __restrict__ out){
  int tid = threadIdx.x;
  float ls = 0.f, hc = 0.f;
  #pragma unroll
  for (int k = 0; k < 4; ++k){
    int i = k * 1024 + tid;
    int pii = (scnt[i] > 0) ? 1 : 0;
    int pm = 2 * poscnt[i] - pii;        // pos_m row count (self col removed)
    if (pm > 0){
      float ps = possum[i];
      float neg = total[i] - ps;
      ls += logf((ps + neg + 1e-8f) / ps);
      hc += 1.f;
    }
  }
  ls += __shfl_xor(ls, 1);  ls += __shfl_xor(ls, 2);  ls += __shfl_xor(ls, 4);
  ls += __shfl_xor(ls, 8);  ls += __shfl_xor(ls, 16); ls += __shfl_xor(ls, 32);
  hc += __shfl_xor(hc, 1);  hc += __shfl_xor(hc, 2);  hc += __shfl_xor(hc, 4);
  hc += __shfl_xor(hc, 8);  hc += __shfl_xor(hc, 16); hc += __shfl_xor(hc, 32);
  __shared__ float sl[16], sh[16];
  if ((tid & 63) == 0){ sl[tid >> 6] = ls; sh[tid >> 6] = hc; }
  __syncthreads();
  if (tid == 0){
    float S = 0.f, H = 0.f;
    #pragma unroll
    for (int w2 = 0; w2 < 16; ++w2){ S += sl[w2]; H += sh[w2]; }
    out[0] = S / fmaxf(H, 1.f);
  }
}

extern "C" void kernel_launch(void* const* d_in, const int* in_sizes, int n_in,
                              void* d_out, int out_size, void* d_ws, size_t ws_size,
                              hipStream_t stream){
  (void)in_sizes; (void)n_in; (void)out_size; (void)ws_size;
  const float* feat   = (const float*)d_in[0];
  const float* labels = (const float*)d_in[1];
  float* out = (float*)d_out;
  char* ws = (char*)d_ws;
  unsigned short* ctr       = (unsigned short*)(ws);               // 4,194,304 B
  unsigned long long* posw  = (unsigned long long*)(ws + 4194304); // 2,097,152 B
  ulonglong2* bits          = (ulonglong2*)(ws + 6291456);         //    65,536 B
  int* scnt                 = (int*)(ws + 6356992);                //    16,384 B
  float* possum             = (float*)(ws + 6373376);              //    16,384 B
  float* total              = (float*)(ws + 6389760);              //    16,384 B
  int* poscnt               = (int*)(ws + 6406144);                //    16,384 B

  hipLaunchKernelGGL(prep_kernel, dim3(1040), dim3(256),  0, stream, labels, feat, bits, scnt, ctr, possum, total, poscnt);
  hipLaunchKernelGGL(pos_kernel,  dim3(4096), dim3(256),  0, stream, bits, scnt, posw, poscnt);
  hipLaunchKernelGGL(gemm_kernel, dim3(1552), dim3(256),  0, stream, ctr, posw, total, possum);
  hipLaunchKernelGGL(fin_kernel,  dim3(1),    dim3(1024), 0, stream, possum, total, poscnt, scnt, out);
}